// Round 7
// baseline (393.314 us; speedup 1.0000x reference)
//
#include <hip/hip_runtime.h>

#define DI __device__ __forceinline__

typedef unsigned short u16;
typedef __attribute__((ext_vector_type(8))) short bf16x8;
typedef __attribute__((ext_vector_type(8))) unsigned short u16x8;
typedef __attribute__((ext_vector_type(4))) float f32x4;

static constexpr int Cc = 256;
static constexpr int Nn = 4096;   // 64*64 spatial

DI float hswish(float v) { return v * fminf(fmaxf(v + 3.f, 0.f), 6.f) * (1.f / 6.f); }

DI u16 f2b(float f) {
  union { float f; unsigned int u; } c; c.f = f;
  return (u16)((c.u + 0x7FFFu + ((c.u >> 16) & 1u)) >> 16);
}
DI float b2f(u16 v) {
  union { unsigned int u; float f; } c; c.u = ((unsigned int)v) << 16; return c.f;
}
DI u16x8 pack8(float4 a, float4 b) {
  u16x8 r;
  r[0] = f2b(a.x); r[1] = f2b(a.y); r[2] = f2b(a.z); r[3] = f2b(a.w);
  r[4] = f2b(b.x); r[5] = f2b(b.y); r[6] = f2b(b.z); r[7] = f2b(b.w);
  return r;
}

// Raw barrier with LDS-visibility wait; vmcnt NOT drained (reg-destined
// prefetch loads stay in flight across the barrier).
#define SYNC_PIPE()                                                           \
  {                                                                           \
    asm volatile("s_waitcnt lgkmcnt(0)" ::: "memory");                        \
    __builtin_amdgcn_sched_barrier(0);                                        \
    __builtin_amdgcn_s_barrier();                                             \
    __builtin_amdgcn_sched_barrier(0);                                        \
  }

// ---------------------------------------------------------------------------
// K1: qkv gemm, bf16 MFMA, f32 inputs, 2-deep register prefetch pipeline.
// Out[g][c][n] (bf16) = sum_k Wg[c][k] * In[n][k].
// Tile 128c x 128n, K-step 32, double LDS buffers + 2 reg sets (Ra,Rb).
// Step ks: ds_write set(ks) -> buf[ks&1]; issue loads(ks+2) into same set;
// raw barrier; ds_read buf[ks&1] + 16 MFMA.
// ---------------------------------------------------------------------------
__global__ __launch_bounds__(256) void k_qkv(
    const float* __restrict__ x, const float* __restrict__ seg,
    const float* __restrict__ kv_w, const float* __restrict__ q_w,
    u16* __restrict__ qkv)
{
  __shared__ __align__(16) u16 As[2][4096];
  __shared__ __align__(16) u16 Bs[2][4096];
  const int t = threadIdx.x;
  const int lane = t & 63, wave = t >> 6;
  const int n0 = blockIdx.x * 128;
  const int c0 = blockIdx.y * 128;
  const int g  = blockIdx.z;
  const int grp = g >> 3, b = g & 7;
  const float* __restrict__ In = (grp == 0 ? seg : x) + (size_t)b * Nn * Cc;
  const float* __restrict__ Wg = (grp == 0) ? q_w : (kv_w + (grp == 2 ? Cc * Cc : 0));

  const int rA = lane & 15;
  const int kA = (lane >> 4) * 8;
  const int s0 = wave * 2, s1 = wave * 2 + 1;
  const float* __restrict__ ap0 = Wg + (size_t)(c0 + s0 * 16 + rA) * Cc + kA;
  const float* __restrict__ ap1 = Wg + (size_t)(c0 + s1 * 16 + rA) * Cc + kA;
  const float* __restrict__ bp0 = In + (size_t)(n0 + s0 * 16 + rA) * Cc + kA;
  const float* __restrict__ bp1 = In + (size_t)(n0 + s1 * 16 + rA) * Cc + kA;

  float4 Ra[8], Rb[8];

#define LOADS(R, k0)                                                          \
  {                                                                           \
    R[0] = *(const float4*)(ap0 + (k0)); R[1] = *(const float4*)(ap0 + (k0) + 4); \
    R[2] = *(const float4*)(ap1 + (k0)); R[3] = *(const float4*)(ap1 + (k0) + 4); \
    R[4] = *(const float4*)(bp0 + (k0)); R[5] = *(const float4*)(bp0 + (k0) + 4); \
    R[6] = *(const float4*)(bp1 + (k0)); R[7] = *(const float4*)(bp1 + (k0) + 4); \
  }
#define WRITES(R, buf)                                                        \
  {                                                                           \
    *(u16x8*)&As[buf][s0 * 512 + lane * 8] = pack8(R[0], R[1]);               \
    *(u16x8*)&As[buf][s1 * 512 + lane * 8] = pack8(R[2], R[3]);               \
    *(u16x8*)&Bs[buf][s0 * 512 + lane * 8] = pack8(R[4], R[5]);               \
    *(u16x8*)&Bs[buf][s1 * 512 + lane * 8] = pack8(R[6], R[7]);               \
  }

  f32x4 acc[4][4];
#pragma unroll
  for (int m = 0; m < 4; ++m)
#pragma unroll
    for (int n = 0; n < 4; ++n) acc[m][n] = (f32x4){0.f, 0.f, 0.f, 0.f};

  const int asub = (wave >> 1) * 4;
  const int bsub = (wave & 1) * 4;

#define COMPUTE(cur)                                                          \
  {                                                                           \
    bf16x8 af[4], bfr[4];                                                     \
    _Pragma("unroll")                                                         \
    for (int m = 0; m < 4; ++m)                                               \
      af[m] = *(const bf16x8*)&As[cur][(asub + m) * 512 + lane * 8];          \
    _Pragma("unroll")                                                         \
    for (int n = 0; n < 4; ++n)                                               \
      bfr[n] = *(const bf16x8*)&Bs[cur][(bsub + n) * 512 + lane * 8];         \
    _Pragma("unroll")                                                         \
    for (int m = 0; m < 4; ++m)                                               \
      _Pragma("unroll")                                                       \
      for (int n = 0; n < 4; ++n)                                             \
        acc[m][n] = __builtin_amdgcn_mfma_f32_16x16x32_bf16(af[m], bfr[n], acc[m][n], 0, 0, 0); \
  }

  LOADS(Ra, 0);
  LOADS(Rb, 32);
#pragma unroll
  for (int kk = 0; kk < 4; ++kk) {
    WRITES(Ra, 0);
    if (kk < 3) LOADS(Ra, (kk * 2 + 2) * 32);
    SYNC_PIPE();
    COMPUTE(0);
    WRITES(Rb, 1);
    if (kk < 3) LOADS(Rb, (kk * 2 + 3) * 32);
    SYNC_PIPE();
    COMPUTE(1);
  }
#undef LOADS
#undef WRITES
#undef COMPUTE

  const int wc = (wave >> 1) * 64, wn = (wave & 1) * 64;
  const int row4 = (lane >> 4) * 4, col = lane & 15;
  u16* __restrict__ op = qkv + (size_t)(g * Cc + c0 + wc) * Nn + n0 + wn;
#pragma unroll
  for (int m = 0; m < 4; ++m)
#pragma unroll
    for (int nn = 0; nn < 4; ++nn)
#pragma unroll
      for (int r = 0; r < 4; ++r)
        op[(size_t)(m * 16 + row4 + r) * Nn + nn * 16 + col] = f2b(acc[m][nn][r]);
}

// ---------------------------------------------------------------------------
// Depthwise conv on one 64x64 plane, f32 LDS (stride 72, col offset 4),
// bf16 in/out. Register-rolled rows.
// ---------------------------------------------------------------------------
template <int KS>
DI void dw_plane(const float* __restrict__ sp, const float* __restrict__ wl,
                 u16* __restrict__ dst, float bias, int t)
{
  constexpr int P = KS / 2;
  float wr[KS * KS];
#pragma unroll
  for (int i = 0; i < KS * KS; ++i) wr[i] = wl[i];
  const int x = t & 63;
  const int yb = (t >> 6) << 4;
  float acc[16];
#pragma unroll
  for (int i = 0; i < 16; ++i) acc[i] = bias;
#pragma unroll
  for (int r = 0; r < 16 + 2 * P; ++r) {
    float v[KS];
    const float* rp = sp + (yb + r + (3 - P)) * 72 + x + (4 - P);
#pragma unroll
    for (int dx = 0; dx < KS; ++dx) v[dx] = rp[dx];
#pragma unroll
    for (int dy = 0; dy < KS; ++dy) {
      const int yl = r - dy;
      if (yl >= 0 && yl < 16) {
        float s = acc[yl];
#pragma unroll
        for (int dx = 0; dx < KS; ++dx) s += wr[dy * KS + dx] * v[dx];
        acc[yl] = s;
      }
    }
  }
#pragma unroll
  for (int yl = 0; yl < 16; ++yl) dst[(yb + yl) * 64 + x] = f2b(acc[yl]);
}

DI void dw_stage(const u16* __restrict__ src, float* __restrict__ sp, int t)
{
  // zero apron: rows {0,1,2,67,68,69} full + cols {0..3,68..71} of rows 3..66
  for (int i = t; i < 944; i += 256) {
    if (i < 432) {
      int r6 = i / 72, cl = i - r6 * 72;
      int row = (r6 < 3) ? r6 : 64 + r6;
      sp[row * 72 + cl] = 0.f;
    } else {
      int i2 = i - 432;
      int row = 3 + (i2 >> 3), k = i2 & 7;
      int cl = (k < 4) ? k : 64 + k;
      sp[row * 72 + cl] = 0.f;
    }
  }
#pragma unroll
  for (int i = 0; i < 2; ++i) {
    int u = t + i * 256;
    int row = u >> 3, c8 = (u & 7) * 8;
    u16x8 v = *(const u16x8*)(src + row * 64 + c8);
    float4 f0 = make_float4(b2f(v[0]), b2f(v[1]), b2f(v[2]), b2f(v[3]));
    float4 f1 = make_float4(b2f(v[4]), b2f(v[5]), b2f(v[6]), b2f(v[7]));
    *(float4*)&sp[(row + 3) * 72 + 4 + c8] = f0;
    *(float4*)&sp[(row + 3) * 72 + 8 + c8] = f1;
  }
}

// K2: all depthwise convs feeding the pw stages (bf16 in/out).
__global__ __launch_bounds__(256) void k_dw(
    const u16* __restrict__ qkv,
    const float* __restrict__ a1w, const float* __restrict__ a2w,
    const float* __restrict__ a3w, const float* __restrict__ a0w,
    u16* __restrict__ dwout, u16* __restrict__ dwout0)
{
  __shared__ float sp[70 * 72];
  __shared__ float wl[49];
  const int t = threadIdx.x;
  const int p = blockIdx.x;
  const u16* src; u16* dst; const float* wsp; int ks;
  if (p < 4608) {
    int g = p / 192, c = p % 192, r = c >> 6;
    ks = 3 + 2 * r;
    wsp = (r == 0 ? a1w : (r == 1 ? a2w : a3w)) + (c & 63) * ks * ks;
    src = qkv + (size_t)(g * 256 + c) * Nn;
    dst = dwout + (size_t)p * Nn;
  } else {
    int q = p - 4608;
    int b = q / 192, j = q % 192;
    ks = 3;
    wsp = a0w + j * 9;
    src = qkv + (size_t)(((j >> 6) * 8 + b) * 256 + 192 + (j & 63)) * Nn;
    dst = dwout0 + (size_t)q * Nn;
  }
  if (t < 49) wl[t] = (t < ks * ks) ? wsp[t] : 0.f;
  dw_stage(src, sp, t);
  __syncthreads();
  if (ks == 3)      dw_plane<3>(sp, wl, dst, 0.f, t);
  else if (ks == 5) dw_plane<5>(sp, wl, dst, 0.f, t);
  else              dw_plane<7>(sp, wl, dst, 0.f, t);
}

// K7: crpe depthwise convs on the V images (bf16 in/out, bias).
__global__ __launch_bounds__(256) void k_crpe(
    const u16* __restrict__ xc,
    const float* __restrict__ w3, const float* __restrict__ b3,
    const float* __restrict__ w5, const float* __restrict__ b5,
    const float* __restrict__ w7, const float* __restrict__ b7,
    u16* __restrict__ conv_v)
{
  __shared__ float sp[70 * 72];
  __shared__ float wl[49];
  const int t = threadIdx.x;
  const int p = blockIdx.x;               // b*192 + ch
  const int b = p / 192, ch = p % 192;
  const float* wsp; float bias; int ks;
  if (ch < 48)       { ks = 3; wsp = w3 + ch * 9;          bias = b3[ch]; }
  else if (ch < 120) { ks = 5; wsp = w5 + (ch - 48) * 25;  bias = b5[ch - 48]; }
  else               { ks = 7; wsp = w7 + (ch - 120) * 49; bias = b7[ch - 120]; }
  const u16* src = xc + (size_t)((16 + b) * 192 + ch) * Nn;
  u16* dst = conv_v + (size_t)p * Nn;
  if (t < 49) wl[t] = (t < ks * ks) ? wsp[t] : 0.f;
  dw_stage(src, sp, t);
  __syncthreads();
  if (ks == 3)      dw_plane<3>(sp, wl, dst, bias, t);
  else if (ks == 5) dw_plane<5>(sp, wl, dst, bias, t);
  else              dw_plane<7>(sp, wl, dst, bias, t);
}

// ---------------------------------------------------------------------------
// K3: pointwise 64->64 + BN + hardswish via bf16 MFMA -> xc[g][r*64+co][n]
// ---------------------------------------------------------------------------
__global__ __launch_bounds__(256) void k_pw_bn(
    const u16* __restrict__ dwout,
    const float* __restrict__ w1, const float* __restrict__ w2, const float* __restrict__ w3,
    const float* __restrict__ g1, const float* __restrict__ be1, const float* __restrict__ m1, const float* __restrict__ v1,
    const float* __restrict__ g2, const float* __restrict__ be2, const float* __restrict__ m2, const float* __restrict__ v2,
    const float* __restrict__ g3, const float* __restrict__ be3, const float* __restrict__ m3, const float* __restrict__ v3,
    u16* __restrict__ xc)
{
  constexpr int S2 = 134;
  __shared__ u16 Dl[64 * S2];
  __shared__ __align__(16) u16 Wt[64 * 72];
  __shared__ float scA[64], shA[64];
  const int t = threadIdx.x;
  const int lane = t & 63, wave = t >> 6;
  const int n0 = blockIdx.x * 128;
  const int r = blockIdx.y;
  const int g = blockIdx.z;
  const float* Wp = (r == 0 ? w1 : (r == 1 ? w2 : w3));
  const float* bg = (r == 0 ? g1 : (r == 1 ? g2 : g3));
  const float* bb = (r == 0 ? be1 : (r == 1 ? be2 : be3));
  const float* bm = (r == 0 ? m1 : (r == 1 ? m2 : m3));
  const float* bv = (r == 0 ? v1 : (r == 1 ? v2 : v3));

  {   // weights -> Wt
    int co = t >> 2, ci0 = (t & 3) * 16;
    const float* wp = Wp + co * 64 + ci0;
    float4 w0 = *(const float4*)wp,       wq = *(const float4*)(wp + 4);
    float4 w2_ = *(const float4*)(wp + 8), w3_ = *(const float4*)(wp + 12);
    *(u16x8*)&Wt[co * 72 + ci0] = pack8(w0, wq);
    *(u16x8*)&Wt[co * 72 + ci0 + 8] = pack8(w2_, w3_);
  }
  if (t < 64) {
    float sc = bg[t] * rsqrtf(bv[t] + 1e-5f);
    scA[t] = sc; shA[t] = bb[t] - bm[t] * sc;
  }
  const u16* dbase = dwout + (size_t)(g * 192 + r * 64) * Nn + n0;
#pragma unroll
  for (int i2 = 0; i2 < 4; ++i2) {
    int u = t + i2 * 256;
    int ci = u >> 4, nu = u & 15;
    u16x8 v = *(const u16x8*)(dbase + (size_t)ci * Nn + nu * 8);
    union { u16x8 v; unsigned int w[4]; } cc; cc.v = v;
    int base = ci * S2 + nu * 8;
#pragma unroll
    for (int w = 0; w < 4; ++w) *(unsigned int*)&Dl[base + 2 * w] = cc.w[w];
  }
  __syncthreads();

  f32x4 acc[4][2];
#pragma unroll
  for (int m = 0; m < 4; ++m)
#pragma unroll
    for (int n = 0; n < 2; ++n) acc[m][n] = (f32x4){0.f, 0.f, 0.f, 0.f};

#pragma unroll
  for (int ks = 0; ks < 2; ++ks) {
    const int kbase = ks * 32 + (lane >> 4) * 8;
    bf16x8 af[4];
#pragma unroll
    for (int m = 0; m < 4; ++m)
      af[m] = *(const bf16x8*)&Wt[(m * 16 + (lane & 15)) * 72 + kbase];
#pragma unroll
    for (int nl = 0; nl < 2; ++nl) {
      const int ncol = (wave * 2 + nl) * 16 + (lane & 15);
      bf16x8 bf;
#pragma unroll
      for (int j = 0; j < 8; ++j) bf[j] = (short)Dl[(kbase + j) * S2 + ncol];
#pragma unroll
      for (int m = 0; m < 4; ++m)
        acc[m][nl] = __builtin_amdgcn_mfma_f32_16x16x32_bf16(af[m], bf, acc[m][nl], 0, 0, 0);
    }
  }

  const int row4 = (lane >> 4) * 4, col = lane & 15;
#pragma unroll
  for (int m = 0; m < 4; ++m)
#pragma unroll
    for (int nl = 0; nl < 2; ++nl) {
      int nn = (wave * 2 + nl) * 16 + col;
      u16* op = xc + (size_t)(g * 192 + r * 64 + m * 16 + row4) * Nn + n0 + nn;
#pragma unroll
      for (int rr = 0; rr < 4; ++rr) {
        int co = m * 16 + row4 + rr;
        float v = acc[m][nl][rr] * scA[co] + shA[co];
        op[(size_t)rr * Nn] = f2b(hswish(v));
      }
    }
}

// ---------------------------------------------------------------------------
// K4: agg0 pointwise 192->64 + in-register layernorm + hardswish
// -> x_agg0[b][n][co] bf16. MFMA, K chunked by 64.
// ---------------------------------------------------------------------------
__global__ __launch_bounds__(256) void k_pw_ln(
    const u16* __restrict__ dwout0, const float* __restrict__ pw,
    const float* __restrict__ lng, const float* __restrict__ lnb,
    u16* __restrict__ x_agg0)
{
  constexpr int S2 = 134;
  __shared__ u16 Dl[64 * S2];
  __shared__ __align__(16) u16 Wt[64 * 200];
  __shared__ float lgA[64], lbA[64];
  const int t = threadIdx.x;
  const int lane = t & 63, wave = t >> 6;
  const int n0 = blockIdx.x * 128;
  const int b = blockIdx.y;

#pragma unroll
  for (int i = 0; i < 12; ++i) {
    int u = t + i * 256;                  // < 3072 float4 units
    int co = u / 48, rem = u - co * 48;
    float4 w = *(const float4*)(pw + co * 192 + rem * 4);
    ushort4 o; o.x = f2b(w.x); o.y = f2b(w.y); o.z = f2b(w.z); o.w = f2b(w.w);
    *(ushort4*)&Wt[co * 200 + rem * 4] = o;
  }
  if (t < 64) { lgA[t] = lng[t]; lbA[t] = lnb[t]; }

  f32x4 acc[4][2];
#pragma unroll
  for (int m = 0; m < 4; ++m)
#pragma unroll
    for (int n = 0; n < 2; ++n) acc[m][n] = (f32x4){0.f, 0.f, 0.f, 0.f};

  for (int kc = 0; kc < 192; kc += 64) {
    if (kc) __syncthreads();
    const u16* dbase = dwout0 + (size_t)(b * 192 + kc) * Nn + n0;
#pragma unroll
    for (int i2 = 0; i2 < 4; ++i2) {
      int u = t + i2 * 256;
      int ci = u >> 4, nu = u & 15;
      u16x8 v = *(const u16x8*)(dbase + (size_t)ci * Nn + nu * 8);
      union { u16x8 v; unsigned int w[4]; } cc; cc.v = v;
      int base = ci * S2 + nu * 8;
#pragma unroll
      for (int w = 0; w < 4; ++w) *(unsigned int*)&Dl[base + 2 * w] = cc.w[w];
    }
    __syncthreads();
#pragma unroll
    for (int ks = 0; ks < 2; ++ks) {
      const int kbase = ks * 32 + (lane >> 4) * 8;
      bf16x8 af[4];
#pragma unroll
      for (int m = 0; m < 4; ++m)
        af[m] = *(const bf16x8*)&Wt[(m * 16 + (lane & 15)) * 200 + kc + kbase];
#pragma unroll
      for (int nl = 0; nl < 2; ++nl) {
        const int ncol = (wave * 2 + nl) * 16 + (lane & 15);
        bf16x8 bf;
#pragma unroll
        for (int j = 0; j < 8; ++j) bf[j] = (short)Dl[(kbase + j) * S2 + ncol];
#pragma unroll
        for (int m = 0; m < 4; ++m)
          acc[m][nl] = __builtin_amdgcn_mfma_f32_16x16x32_bf16(af[m], bf, acc[m][nl], 0, 0, 0);
      }
    }
  }

  const int row4 = (lane >> 4) * 4, col = lane & 15;
#pragma unroll
  for (int nl = 0; nl < 2; ++nl) {
    float s = 0.f, q = 0.f;
#pragma unroll
    for (int m = 0; m < 4; ++m)
#pragma unroll
      for (int rr = 0; rr < 4; ++rr) {
        float v = acc[m][nl][rr];
        s += v; q += v * v;
      }
    s += __shfl_xor(s, 16, 64); q += __shfl_xor(q, 16, 64);
    s += __shfl_xor(s, 32, 64); q += __shfl_xor(q, 32, 64);
    float mu = s * (1.f / 64.f);
    float var = q * (1.f / 64.f) - mu * mu;
    float is = rsqrtf(var + 1e-5f);
    int nn = (wave * 2 + nl) * 16 + col;
    u16* op = x_agg0 + (size_t)((b << 12) + n0 + nn) * 64;
#pragma unroll
    for (int m = 0; m < 4; ++m) {
      ushort4 o;
#pragma unroll
      for (int rr = 0; rr < 4; ++rr) {
        int co = m * 16 + row4 + rr;
        float v = (acc[m][nl][rr] - mu) * is * lgA[co] + lbA[co];
        ((u16*)&o)[rr] = f2b(hswish(v));
      }
      *(ushort4*)&op[m * 16 + row4] = o;
    }
  }
}

// ---------------------------------------------------------------------------
// K6: ktv_raw[b,h,k,v] = sum_n exp(kh) * vh  and  Z[b,h,k] = sum_n exp(kh).
// No max-subtraction: kh ~ N(0,0.8^2) after bf16 gemm -> exp bounded ~e^6,
// Z <= 4096*e^6 << f32 max. 8 N-chunks, atomicAdd.
// ---------------------------------------------------------------------------
__global__ __launch_bounds__(576) void k_ktv(const u16* __restrict__ xc,
                                             float* __restrict__ ktv,
                                             float* __restrict__ Z)
{
  __shared__ float pb[24][65];
  __shared__ float vb[24][65];
  const int nc = blockIdx.x, h = blockIdx.y, b = blockIdx.z;
  const int t = threadIdx.x;
  const int kk = t / 24, vv = t - kk * 24;
  const u16* kbase = xc + (size_t)((8 + b) * 192 + h * 24) * Nn;
  const u16* vbase = xc + (size_t)((16 + b) * 192 + h * 24) * Nn;
  const int nb0 = nc * 512;
  float accv = 0.f, accz = 0.f;
  for (int sub = 0; sub < 8; ++sub) {
    if (sub) __syncthreads();
    int nbase = nb0 + sub * 64;
    if (t < 384) {
      int which = t >= 192;
      int i = which ? t - 192 : t;
      int ch = i >> 3, c8 = (i & 7) * 8;
      const u16* sp = (which ? vbase : kbase) + (size_t)ch * Nn + nbase + c8;
      u16x8 v = *(const u16x8*)sp;
      float* dst = which ? &vb[ch][c8] : &pb[ch][c8];
      if (!which) {
#pragma unroll
        for (int j = 0; j < 8; ++j) dst[j] = __expf(b2f(v[j]));
      } else {
#pragma unroll
        for (int j = 0; j < 8; ++j) dst[j] = b2f(v[j]);
      }
    }
    __syncthreads();
    float a = 0.f, z = 0.f;
#pragma unroll 16
    for (int i = 0; i < 64; ++i) { float p = pb[kk][i]; a += p * vb[vv][i]; z += p; }
    accv += a; accz += z;
  }
  atomicAdd(&ktv[((b * 8 + h) * 24 + kk) * 24 + vv], accv);
  if (vv == 0) atomicAdd(&Z[(b * 8 + h) * 24 + kk], accz);
}

// ---------------------------------------------------------------------------
// K8: assemble catb (bf16): [b][n][0:192] = scale*(q@(ktv/Z)) + q*conv_v,
// [192:256] = x_agg0 copy. ktv normalized by Z at LDS-stage time.
// ---------------------------------------------------------------------------
__global__ __launch_bounds__(256) void k_cat(
    const u16* __restrict__ xc, const u16* __restrict__ conv_v,
    const float* __restrict__ ktv, const float* __restrict__ Z,
    const u16* __restrict__ x_agg0, u16* __restrict__ catb)
{
  __shared__ float kt[4608];
  const int t = threadIdx.x;
  const int b = blockIdx.y;
  for (int e = t; e < 4608; e += 256) {
    int h = e / 576, rem = e - h * 576, k = rem / 24;
    kt[e] = ktv[b * 4608 + e] / Z[b * 192 + h * 24 + k];
  }
  __syncthreads();
  const int nl = t & 63;
  const int grp = t >> 6;
  const int n = blockIdx.x * 64 + nl;
  const float scale = 0.17677669529663687f;   // 32^-0.5
#pragma unroll
  for (int hh = 0; hh < 2; ++hh) {
    const int h = grp * 2 + hh;
    const u16* qb = xc + (size_t)(b * 192 + h * 24) * Nn + n;
    float q[24];
#pragma unroll
    for (int c = 0; c < 24; ++c) q[c] = b2f(qb[(size_t)c * Nn]);
    float ev[24];
#pragma unroll
    for (int v = 0; v < 24; ++v) ev[v] = 0.f;
    const float* kth = kt + h * 576;
#pragma unroll
    for (int k = 0; k < 24; ++k) {
      const float qk = q[k];
#pragma unroll
      for (int v = 0; v < 24; ++v) ev[v] += qk * kth[k * 24 + v];
    }
    const u16* cvb = conv_v + (size_t)(b * 192 + h * 24) * Nn + n;
    u16* ob = catb + ((size_t)(b * 4096 + n)) * 256 + h * 24;
#pragma unroll
    for (int v4 = 0; v4 < 6; ++v4) {
      ushort4 o;
      o.x = f2b(scale * ev[v4 * 4 + 0] + q[v4 * 4 + 0] * b2f(cvb[(size_t)(v4 * 4 + 0) * Nn]));
      o.y = f2b(scale * ev[v4 * 4 + 1] + q[v4 * 4 + 1] * b2f(cvb[(size_t)(v4 * 4 + 1) * Nn]));
      o.z = f2b(scale * ev[v4 * 4 + 2] + q[v4 * 4 + 2] * b2f(cvb[(size_t)(v4 * 4 + 2) * Nn]));
      o.w = f2b(scale * ev[v4 * 4 + 3] + q[v4 * 4 + 3] * b2f(cvb[(size_t)(v4 * 4 + 3) * Nn]));
      *(ushort4*)(ob + v4 * 4) = o;
    }
  }
  const u16* xa = x_agg0 + ((size_t)(b * 4096 + blockIdx.x * 64)) * 64;
  u16* cb = catb + ((size_t)(b * 4096 + blockIdx.x * 64)) * 256 + 192;
  for (int e2 = t; e2 < 4096; e2 += 256) {
    int nn = e2 >> 6, cc = e2 & 63;
    cb[(size_t)nn * 256 + cc] = xa[(size_t)nn * 64 + cc];
  }
}

// ---------------------------------------------------------------------------
// K9: out[m][c] = sum_k catb[m][k]*proj_w[c][k] + pb[c].
// Same 2-deep reg-prefetch pipeline as k_qkv. A bf16 direct, B f32 packed.
// ---------------------------------------------------------------------------
__global__ __launch_bounds__(256) void k_proj(
    const u16* __restrict__ catb, const float* __restrict__ pwf,
    const float* __restrict__ pb, float* __restrict__ out)
{
  __shared__ __align__(16) u16 As[2][4096];
  __shared__ __align__(16) u16 Bs[2][4096];
  const int t = threadIdx.x;
  const int lane = t & 63, wave = t >> 6;
  const int m0 = blockIdx.x * 128;
  const int c0 = blockIdx.y * 128;
  const int rA = lane & 15;
  const int kA = (lane >> 4) * 8;
  const int s0 = wave * 2, s1 = wave * 2 + 1;
  const u16*   __restrict__ aq0 = catb + (size_t)(m0 + s0 * 16 + rA) * 256 + kA;
  const u16*   __restrict__ aq1 = catb + (size_t)(m0 + s1 * 16 + rA) * 256 + kA;
  const float* __restrict__ bp0 = pwf + (size_t)(c0 + s0 * 16 + rA) * 256 + kA;
  const float* __restrict__ bp1 = pwf + (size_t)(c0 + s1 * 16 + rA) * 256 + kA;

  u16x8 Ua[2], Ub[2];
  float4 Fa[4], Fb[4];

#define LOADS(U, F, k0)                                                       \
  {                                                                           \
    U[0] = *(const u16x8*)(aq0 + (k0));                                       \
    U[1] = *(const u16x8*)(aq1 + (k0));                                       \
    F[0] = *(const float4*)(bp0 + (k0)); F[1] = *(const float4*)(bp0 + (k0) + 4); \
    F[2] = *(const float4*)(bp1 + (k0)); F[3] = *(const float4*)(bp1 + (k0) + 4); \
  }
#define WRITES(U, F, buf)                                                     \
  {                                                                           \
    *(u16x8*)&As[buf][s0 * 512 + lane * 8] = U[0];                            \
    *(u16x8*)&As[buf][s1 * 512 + lane * 8] = U[1];                            \
    *(u16x8*)&Bs[buf][s0 * 512 + lane * 8] = pack8(F[0], F[1]);               \
    *(u16x8*)&Bs[buf][s1 * 512 + lane * 8] = pack8(F[2], F[3]);               \
  }

  f32x4 acc[4][4];
#pragma unroll
  for (int m = 0; m < 4; ++m)
#pragma unroll
    for (int n = 0; n < 4; ++n) acc[m][n] = (f32x4){0.f, 0.f, 0.f, 0.f};

  const int asub = (wave >> 1) * 4;
  const int bsub = (wave & 1) * 4;

#define COMPUTE(cur)                                                          \
  {                                                                           \
    bf16x8 af[4], bfr[4];                                                     \
    _Pragma("unroll")                                                         \
    for (int m = 0; m < 4; ++m)                                               \
      af[m] = *(const bf16x8*)&As[cur][(asub + m) * 512 + lane * 8];          \
    _Pragma("unroll")                                                         \
    for (int n = 0; n < 4; ++n)                                               \
      bfr[n] = *(const bf16x8*)&Bs[cur][(bsub + n) * 512 + lane * 8];         \
    _Pragma("unroll")                                                         \
    for (int m = 0; m < 4; ++m)                                               \
      _Pragma("unroll")                                                       \
      for (int n = 0; n < 4; ++n)                                             \
        acc[m][n] = __builtin_amdgcn_mfma_f32_16x16x32_bf16(af[m], bfr[n], acc[m][n], 0, 0, 0); \
  }

  LOADS(Ua, Fa, 0);
  LOADS(Ub, Fb, 32);
#pragma unroll
  for (int kk = 0; kk < 4; ++kk) {
    WRITES(Ua, Fa, 0);
    if (kk < 3) LOADS(Ua, Fa, (kk * 2 + 2) * 32);
    SYNC_PIPE();
    COMPUTE(0);
    WRITES(Ub, Fb, 1);
    if (kk < 3) LOADS(Ub, Fb, (kk * 2 + 3) * 32);
    SYNC_PIPE();
    COMPUTE(1);
  }
#undef LOADS
#undef WRITES
#undef COMPUTE

  const int wm = (wave >> 1) * 64, wn = (wave & 1) * 64;
  const int row4 = (lane >> 4) * 4, col = lane & 15;
  float pbv[4];
#pragma unroll
  for (int nn = 0; nn < 4; ++nn) pbv[nn] = pb[c0 + wn + nn * 16 + col];
  float* __restrict__ op = out + (size_t)(m0 + wm) * 256 + c0 + wn;
#pragma unroll
  for (int mi = 0; mi < 4; ++mi)
#pragma unroll
    for (int nn = 0; nn < 4; ++nn)
#pragma unroll
      for (int r = 0; r < 4; ++r)
        op[(size_t)(mi * 16 + row4 + r) * 256 + nn * 16 + col] = acc[mi][nn][r] + pbv[nn];
}

// ---------------------------------------------------------------------------
extern "C" void kernel_launch(void* const* d_in, const int* in_sizes, int n_in,
                              void* d_out, int out_size, void* d_ws, size_t ws_size,
                              hipStream_t stream)
{
  const float* x       = (const float*)d_in[0];
  const float* seg     = (const float*)d_in[1];
  const float* kv_w    = (const float*)d_in[2];
  const float* q_w     = (const float*)d_in[3];
  const float* proj_w  = (const float*)d_in[4];
  const float* proj_b  = (const float*)d_in[5];
  const float* agg0_dw = (const float*)d_in[6];
  const float* agg0_pw = (const float*)d_in[7];
  const float* ln_g    = (const float*)d_in[8];
  const float* ln_b    = (const float*)d_in[9];
  const float* agg1_dw = (const float*)d_in[10];
  const float* agg1_pw = (const float*)d_in[11];
  const float* bn1_g   = (const float*)d_in[12];
  const float* bn1_b   = (const float*)d_in[13];
  const float* bn1_m   = (const float*)d_in[14];
  const float* bn1_v   = (const float*)d_in[15];
  const float* agg2_dw = (const float*)d_in[16];
  const float* agg2_pw = (const float*)d_in[17];
  const float* bn2_g   = (const float*)d_in[18];
  const float* bn2_b   = (const float*)d_in[19];
  const float* bn2_m   = (const float*)d_in[20];
  const float* bn2_v   = (const float*)d_in[21];
  const float* agg3_dw = (const float*)d_in[22];
  const float* agg3_pw = (const float*)d_in[23];
  const float* bn3_g   = (const float*)d_in[24];
  const float* bn3_b   = (const float*)d_in[25];
  const float* bn3_m   = (const float*)d_in[26];
  const float* bn3_v   = (const float*)d_in[27];
  const float* crpe_w3 = (const float*)d_in[28];
  const float* crpe_b3 = (const float*)d_in[29];
  const float* crpe_w5 = (const float*)d_in[30];
  const float* crpe_b5 = (const float*)d_in[31];
  const float* crpe_w7 = (const float*)d_in[32];
  const float* crpe_b7 = (const float*)d_in[33];

  float* ws = (float*)d_ws;
  u16*   qkv_b  = (u16*)(ws);                 // 25165824 u16
  u16*   dwout  = (u16*)(ws + 12582912);      // 18874368 u16
  u16*   dwout0 = (u16*)(ws + 22020096);      //  6291456 u16
  u16*   xc_b   = (u16*)(ws + 25165824);      // 25165824 u16
  u16*   conv_v = (u16*)(ws + 37748736);      //  6291456 u16
  u16*   x_agg0 = (u16*)(ws + 40894464);      //  2097152 u16
  float* Z      = ws + 41943040;              // 1536 f
  float* ktv    = ws + 41944576;              // 36864 f
  u16*   catb   = (u16*)(ws + 41981440);      //  8388608 u16
  float* out    = (float*)d_out;

  hipMemsetAsync(Z, 0, (1536 + 36864) * sizeof(float), stream);

  k_qkv<<<dim3(32, 2, 24), 256, 0, stream>>>(x, seg, kv_w, q_w, qkv_b);
  k_dw<<<dim3(6144), 256, 0, stream>>>(qkv_b, agg1_dw, agg2_dw, agg3_dw, agg0_dw,
                                       dwout, dwout0);
  k_pw_bn<<<dim3(32, 3, 24), 256, 0, stream>>>(
      dwout, agg1_pw, agg2_pw, agg3_pw,
      bn1_g, bn1_b, bn1_m, bn1_v,
      bn2_g, bn2_b, bn2_m, bn2_v,
      bn3_g, bn3_b, bn3_m, bn3_v, xc_b);
  k_pw_ln<<<dim3(32, 8), 256, 0, stream>>>(dwout0, agg0_pw, ln_g, ln_b, x_agg0);
  k_ktv<<<dim3(8, 8, 8), 576, 0, stream>>>(xc_b, ktv, Z);
  k_crpe<<<dim3(1536), 256, 0, stream>>>(xc_b, crpe_w3, crpe_b3, crpe_w5,
                                         crpe_b5, crpe_w7, crpe_b7, conv_v);
  k_cat<<<dim3(64, 8), 256, 0, stream>>>(xc_b, conv_v, ktv, Z, x_agg0, catb);
  k_proj<<<dim3(256, 2), 256, 0, stream>>>(catb, proj_w, proj_b, out);
}